// Round 1
// baseline (1080.367 us; speedup 1.0000x reference)
//
#include <hip/hip_runtime.h>
#include <hip/hip_bf16.h>
#include <math.h>

// Problem constants
#define BLn 32          // B*L
#define Cn 32           // channels
#define Hn 128
#define Wn 256
#define NR 64           // kept rows: 0..31 and 96..127
#define NJ 32           // kept cols: 0..31
#define NMODE (NR*NJ)   // 2048
#define PLANE (Hn*Wn)   // 32768

// Workspace layout (float offsets)
#define OFF_T1C 0u        // [xb=64][j=32] float4: cos(2pi*j*(4xb+m)/256)
#define OFF_T1D 8192u     // same, sin
#define OFF_T1E 16384u    // [j=32][xq=64] float4: cos (transposed for inverse)
#define OFF_T1F 24576u    // same, sin
#define OFF_T2A 32768u    // [i64=64][y2=64] float4: (c(2y2),s(2y2),c(2y2+1),s(2y2+1)), phi=2pi*r(i64)*y/128
#define OFF_T2B 49152u    // [y=128][i2=32] float4: (c(2i2),s(2i2),c(2i2+1),s(2i2+1)) over i64 pairs
#define OFF_KM  65536u    // [mode=2048][c=32] float2
#define OFF_WK  196608u   // [mode=2048][c=32][o=32] float2
#define OFF_XM  4390912u  // [mode=2048][bl=32][c=32] float2 ; reused in-place as Om [mode][bl][o]
// total = 8585216 floats = 32.75 MiB of d_ws

__global__ __launch_bounds__(256) void build_tables(float* __restrict__ ws) {
  int tid = blockIdx.x * 256 + threadIdx.x; // 4096 threads
  const double PI2 = 6.283185307179586476925286766559;
  if (tid < 2048) {
    int xb = tid >> 5, j = tid & 31;
    float cc[4], ss[4];
#pragma unroll
    for (int m = 0; m < 4; m++) {
      int x = xb * 4 + m;
      double ang = PI2 * (double)((j * x) & 255) / 256.0;
      cc[m] = (float)cos(ang); ss[m] = (float)sin(ang);
    }
    float4 c4 = make_float4(cc[0], cc[1], cc[2], cc[3]);
    float4 s4 = make_float4(ss[0], ss[1], ss[2], ss[3]);
    ((float4*)(ws + OFF_T1C))[xb * 32 + j] = c4;
    ((float4*)(ws + OFF_T1D))[xb * 32 + j] = s4;
    ((float4*)(ws + OFF_T1E))[j * 64 + xb] = c4;
    ((float4*)(ws + OFF_T1F))[j * 64 + xb] = s4;
  }
  if (tid < 4096) {
    int i64 = tid >> 6, y2 = tid & 63;
    int r = (i64 < 32) ? i64 : i64 + 64;
    double a0 = PI2 * (double)((r * (2 * y2)) & 127) / 128.0;
    double a1 = PI2 * (double)((r * (2 * y2 + 1)) & 127) / 128.0;
    ((float4*)(ws + OFF_T2A))[i64 * 64 + y2] =
        make_float4((float)cos(a0), (float)sin(a0), (float)cos(a1), (float)sin(a1));
  }
  if (tid < 4096) {
    int y = tid >> 5, i2 = tid & 31;
    int ia = 2 * i2, ib = 2 * i2 + 1;
    int ra = (ia < 32) ? ia : ia + 64;
    int rb = (ib < 32) ? ib : ib + 64;
    double a0 = PI2 * (double)((ra * y) & 127) / 128.0;
    double a1 = PI2 * (double)((rb * y) & 127) / 128.0;
    ((float4*)(ws + OFF_T2B))[y * 32 + i2] =
        make_float4((float)cos(a0), (float)sin(a0), (float)cos(a1), (float)sin(a1));
  }
}

// Partial rfft2 of one 128x256 real plane: keeps rows {0..31,96..127}, cols 0..31.
// Output layout: dst[(i64*32+j)*npl + plane] (mode-major).
__global__ __launch_bounds__(256) void fwd_plane(const float* __restrict__ src,
                                                 float2* __restrict__ dst,
                                                 const float* __restrict__ ws,
                                                 int npl) {
  const int plane = blockIdx.x;
  const float* u = src + (size_t)plane * PLANE;
  const float4* T1c = (const float4*)(ws + OFF_T1C);
  const float4* T1d = (const float4*)(ws + OFF_T1D);
  const float4* T2a = (const float4*)(ws + OFF_T2A);
  __shared__ float2 Rf[Hn * NJ]; // [y][j], 32 KB
  const int t = threadIdx.x;
  const int j = t & 31, yg = t >> 5;

  // Step 1: R[y][j] = sum_x u[y,x] * exp(-2pi i j x/256)
  float ar[16], ai[16];
#pragma unroll
  for (int k = 0; k < 16; k++) { ar[k] = 0.f; ai[k] = 0.f; }
  for (int xb = 0; xb < 64; xb++) {
    float4 c4 = T1c[xb * 32 + j];
    float4 s4 = T1d[xb * 32 + j];
#pragma unroll
    for (int k = 0; k < 16; k++) {
      int y = yg * 16 + k;
      float4 u4 = *(const float4*)(u + y * Wn + xb * 4);
      ar[k] += u4.x * c4.x + u4.y * c4.y + u4.z * c4.z + u4.w * c4.w;
      ai[k] -= u4.x * s4.x + u4.y * s4.y + u4.z * s4.z + u4.w * s4.w;
    }
  }
#pragma unroll
  for (int k = 0; k < 16; k++) Rf[(yg * 16 + k) * 32 + j] = make_float2(ar[k], ai[k]);
  __syncthreads();

  // Step 2: X[i64][j] = sum_y R[y][j] * exp(-2pi i r(i64) y/128)
  float xr[8], xi[8];
#pragma unroll
  for (int m = 0; m < 8; m++) { xr[m] = 0.f; xi[m] = 0.f; }
  for (int y2 = 0; y2 < 64; y2++) {
    float2 r0 = Rf[(2 * y2) * 32 + j];
    float2 r1 = Rf[(2 * y2 + 1) * 32 + j];
#pragma unroll
    for (int m = 0; m < 8; m++) {
      int i64 = yg + 8 * m;
      float4 tw = T2a[i64 * 64 + y2]; // (c0,s0,c1,s1)
      xr[m] += r0.x * tw.x + r0.y * tw.y + r1.x * tw.z + r1.y * tw.w;
      xi[m] += r0.y * tw.x - r0.x * tw.y + r1.y * tw.z - r1.x * tw.w;
    }
  }
#pragma unroll
  for (int m = 0; m < 8; m++) {
    int i64 = yg + 8 * m;
    dst[(size_t)(i64 * 32 + j) * npl + plane] = make_float2(xr[m], xi[m]);
  }
}

// Wk[mode][c][o] = Km[mode][c] * (w1|w2)[c][o][r][j]  (complex)
__global__ __launch_bounds__(256) void wk_build(const float* __restrict__ w1r,
                                                const float* __restrict__ w1i,
                                                const float* __restrict__ w2r,
                                                const float* __restrict__ w2i,
                                                float2* __restrict__ wk,
                                                const float2* __restrict__ km) {
  int e0 = blockIdx.x * 256 + threadIdx.x; // 524288 threads
#pragma unroll
  for (int k = 0; k < 4; k++) {
    int e = e0 + k * 524288;
    int o = e & 31, c = (e >> 5) & 31, j = (e >> 10) & 31, i64 = e >> 15;
    int r = (i64 < 32) ? i64 : i64 - 32;
    const float* wr = (i64 < 32) ? w1r : w2r;
    const float* wi = (i64 < 32) ? w1i : w2i;
    int widx = ((c * 32 + o) * 32 + r) * 32 + j;
    float wrv = wr[widx], wiv = wi[widx];
    float2 kv = km[(i64 * 32 + j) * 32 + c];
    wk[e] = make_float2(kv.x * wrv - kv.y * wiv, kv.x * wiv + kv.y * wrv);
  }
}

// Per-mode channel mixing: Om[mode][bl][o] = sum_c Xm[mode][bl][c] * Wk[mode][c][o]
// In-place on the Xm buffer (each block owns its mode slab exclusively).
__global__ __launch_bounds__(256) void mix_modes(float2* __restrict__ xm,
                                                 const float2* __restrict__ wk) {
  int mode = blockIdx.x; // 0..2047
  __shared__ float2 Xs[1024]; // [bl][c]
  __shared__ float2 Ws[1024]; // [c][o]
  int t = threadIdx.x;
  size_t base = (size_t)mode * 1024;
#pragma unroll
  for (int k = 0; k < 4; k++) {
    Xs[t + 256 * k] = xm[base + t + 256 * k];
    Ws[t + 256 * k] = wk[base + t + 256 * k];
  }
  __syncthreads();
  int o = t & 31, bg = t >> 5;
  float orr[4], oii[4];
#pragma unroll
  for (int m = 0; m < 4; m++) { orr[m] = 0.f; oii[m] = 0.f; }
  for (int c = 0; c < 32; c++) {
    float2 wv = Ws[c * 32 + o];
#pragma unroll
    for (int m = 0; m < 4; m++) {
      float2 xv = Xs[(bg * 4 + m) * 32 + c];
      orr[m] += xv.x * wv.x - xv.y * wv.y;
      oii[m] += xv.x * wv.y + xv.y * wv.x;
    }
  }
#pragma unroll
  for (int m = 0; m < 4; m++)
    xm[base + (size_t)(bg * 4 + m) * 32 + o] = make_float2(orr[m], oii[m]);
}

// Partial irfft2: out[y,x] = (1/(H*W)) * ( Re G[y,0] + 2*sum_{j=1}^{31} (Gr cos - Gi sin) )
// with G[y,j] = sum_{i64} Om[i64,j] * exp(+2pi i r(i64) y / 128)
__global__ __launch_bounds__(256) void inv_plane(const float2* __restrict__ om,
                                                 float* __restrict__ out,
                                                 const float* __restrict__ ws) {
  int p = blockIdx.x; // bl*32 + o
  const float4* T2b = (const float4*)(ws + OFF_T2B);
  const float4* T1e = (const float4*)(ws + OFF_T1E);
  const float4* T1f = (const float4*)(ws + OFF_T1F);
  __shared__ float2 Os[NMODE];   // [i64][j] 16 KB
  __shared__ float2 Gs[Hn * NJ]; // [y][j]  32 KB
  int t = threadIdx.x;
#pragma unroll
  for (int k = 0; k < 8; k++) {
    int mode = t + 256 * k;
    Os[mode] = om[(size_t)mode * 1024 + p];
  }
  __syncthreads();
  int j = t & 31, yg = t >> 5;
  float gr[16], gi[16];
#pragma unroll
  for (int k = 0; k < 16; k++) { gr[k] = 0.f; gi[k] = 0.f; }
  for (int i2 = 0; i2 < 32; i2++) {
    float2 o0 = Os[(2 * i2) * 32 + j];
    float2 o1 = Os[(2 * i2 + 1) * 32 + j];
#pragma unroll
    for (int k = 0; k < 16; k++) {
      int y = yg * 16 + k;
      float4 tw = T2b[y * 32 + i2]; // (c0,s0,c1,s1)
      gr[k] += o0.x * tw.x - o0.y * tw.y + o1.x * tw.z - o1.y * tw.w;
      gi[k] += o0.x * tw.y + o0.y * tw.x + o1.x * tw.w + o1.y * tw.z;
    }
  }
#pragma unroll
  for (int k = 0; k < 16; k++) Gs[(yg * 16 + k) * 32 + j] = make_float2(gr[k], gi[k]);
  __syncthreads();

  int xq = t & 63, ygr = t >> 6;
  float* outp = out + (size_t)p * PLANE;
  const float inv = 1.0f / 32768.0f;
  for (int pass = 0; pass < 32; pass++) {
    int y = pass * 4 + ygr;
    float g0 = Gs[y * 32 + 0].x; // numpy irfft ignores Im of bin 0
    float4 v = make_float4(g0, g0, g0, g0);
    for (int jj = 1; jj < 32; jj++) {
      float2 g = Gs[y * 32 + jj];
      float a = 2.f * g.x, b = 2.f * g.y;
      float4 c4 = T1e[jj * 64 + xq];
      float4 s4 = T1f[jj * 64 + xq];
      v.x += a * c4.x - b * s4.x;
      v.y += a * c4.y - b * s4.y;
      v.z += a * c4.z - b * s4.z;
      v.w += a * c4.w - b * s4.w;
    }
    v.x *= inv; v.y *= inv; v.z *= inv; v.w *= inv;
    *(float4*)(outp + y * Wn + xq * 4) = v;
  }
}

extern "C" void kernel_launch(void* const* d_in, const int* in_sizes, int n_in,
                              void* d_out, int out_size, void* d_ws, size_t ws_size,
                              hipStream_t stream) {
  (void)in_sizes; (void)n_in; (void)out_size; (void)ws_size;
  const float* x   = (const float*)d_in[0];
  const float* kk  = (const float*)d_in[1];
  const float* w1r = (const float*)d_in[2];
  const float* w1i = (const float*)d_in[3];
  const float* w2r = (const float*)d_in[4];
  const float* w2i = (const float*)d_in[5];
  float*  ws  = (float*)d_ws;
  float*  out = (float*)d_out;
  float2* km  = (float2*)(ws + OFF_KM);
  float2* wk  = (float2*)(ws + OFF_WK);
  float2* xm  = (float2*)(ws + OFF_XM);

  build_tables<<<16, 256, 0, stream>>>(ws);
  fwd_plane<<<32, 256, 0, stream>>>(kk, km, ws, 32);
  wk_build<<<2048, 256, 0, stream>>>(w1r, w1i, w2r, w2i, wk, km);
  fwd_plane<<<1024, 256, 0, stream>>>(x, xm, ws, 1024);
  mix_modes<<<2048, 256, 0, stream>>>(xm, wk);
  inv_plane<<<1024, 256, 0, stream>>>(xm, out, ws);
}

// Round 2
// 750.099 us; speedup vs baseline: 1.4403x; 1.4403x over previous
//
#include <hip/hip_runtime.h>
#include <math.h>

// Problem constants
#define Hn 128
#define Wn 256
#define PLANE (Hn*Wn)   // 32768
#define NMODE 2048      // 64 kept rows x 32 kept cols

// Workspace layout (float offsets)
#define OFF_T1C 0u        // [xb=64][j=32] float4 cos(2pi*j*(4xb+m)/256)
#define OFF_T1D 8192u     // sin
#define OFF_T1E 16384u    // [j=32][xq=64] float4 cos (for inverse, +angle)
#define OFF_T1F 24576u    // sin
#define OFF_T2A 32768u    // [i64=64][y2=64] float4 (c,s) pairs, -angle (fwd y-DFT)
#define OFF_T2B 49152u    // [y=128][i2=32] float4 (c,s) pairs, +angle (inv y-DFT)
#define OFF_KM  65536u    // [mode=2048][c=32] float2                    (131072 floats)
#define OFF_XM  196608u   // [mode=2048][plane=1024] float2              (4194304 floats)
#define OFF_B   4390912u  // time-shared: Rx [1024][128][32] float2 (8388608)
                          //              then WK [mode][c][o] float2 (4194304)
                          //              then G' [1024][128][32] float2 (8388608)
#define OFF_RK  12779520u // Rk [32][128][32] float2                     (262144 floats)
// total = 13041664 floats = 52.2 MiB of d_ws

__global__ __launch_bounds__(256) void build_tables(float* __restrict__ ws) {
  int tid = blockIdx.x * 256 + threadIdx.x; // 4096 threads
  const double PI2 = 6.283185307179586476925286766559;
  if (tid < 2048) {
    int xb = tid >> 5, j = tid & 31;
    float cc[4], ss[4];
#pragma unroll
    for (int m = 0; m < 4; m++) {
      int x = xb * 4 + m;
      double ang = PI2 * (double)((j * x) & 255) / 256.0;
      cc[m] = (float)cos(ang); ss[m] = (float)sin(ang);
    }
    float4 c4 = make_float4(cc[0], cc[1], cc[2], cc[3]);
    float4 s4 = make_float4(ss[0], ss[1], ss[2], ss[3]);
    ((float4*)(ws + OFF_T1C))[xb * 32 + j] = c4;
    ((float4*)(ws + OFF_T1D))[xb * 32 + j] = s4;
    ((float4*)(ws + OFF_T1E))[j * 64 + xb] = c4;
    ((float4*)(ws + OFF_T1F))[j * 64 + xb] = s4;
  }
  if (tid < 4096) {
    int i64 = tid >> 6, y2 = tid & 63;
    int r = (i64 < 32) ? i64 : i64 + 64;
    double a0 = PI2 * (double)((r * (2 * y2)) & 127) / 128.0;
    double a1 = PI2 * (double)((r * (2 * y2 + 1)) & 127) / 128.0;
    ((float4*)(ws + OFF_T2A))[i64 * 64 + y2] =
        make_float4((float)cos(a0), (float)sin(a0), (float)cos(a1), (float)sin(a1));
  }
  if (tid < 4096) {
    int y = tid >> 5, i2 = tid & 31;
    int ia = 2 * i2, ib = 2 * i2 + 1;
    int ra = (ia < 32) ? ia : ia + 64;
    int rb = (ib < 32) ? ib : ib + 64;
    double a0 = PI2 * (double)((ra * y) & 127) / 128.0;
    double a1 = PI2 * (double)((rb * y) & 127) / 128.0;
    ((float4*)(ws + OFF_T2B))[y * 32 + i2] =
        make_float4((float)cos(a0), (float)sin(a0), (float)cos(a1), (float)sin(a1));
  }
}

// Stage 1 of rfft2: R[plane][y][j] = sum_x u[plane,y,x] e^{-2pi i j x/256}, j<32.
// Grid: nplanes*4 blocks (32 y each). 8 accum VGPRs/thread.
__global__ __launch_bounds__(256, 4) void fwd_rows(const float* __restrict__ src,
                                                   float2* __restrict__ R,
                                                   const float* __restrict__ ws) {
  int plane = blockIdx.x >> 2, chunk = blockIdx.x & 3;
  const float* u = src + (size_t)plane * PLANE;
  const float4* T1c = (const float4*)(ws + OFF_T1C);
  const float4* T1d = (const float4*)(ws + OFF_T1D);
  int t = threadIdx.x, j = t & 31, yg = t >> 5;
  int ys = chunk * 32 + yg * 4;
  float ar[4] = {0.f, 0.f, 0.f, 0.f}, ai[4] = {0.f, 0.f, 0.f, 0.f};
  for (int xb = 0; xb < 64; xb++) {
    float4 c4 = T1c[xb * 32 + j];
    float4 s4 = T1d[xb * 32 + j];
#pragma unroll
    for (int k = 0; k < 4; k++) {
      float4 u4 = *(const float4*)(u + (ys + k) * Wn + xb * 4);
      ar[k] += u4.x * c4.x + u4.y * c4.y + u4.z * c4.z + u4.w * c4.w;
      ai[k] -= u4.x * s4.x + u4.y * s4.y + u4.z * s4.z + u4.w * s4.w;
    }
  }
#pragma unroll
  for (int k = 0; k < 4; k++)
    R[((size_t)plane * Hn + ys + k) * 32 + j] = make_float2(ar[k], ai[k]);
}

// Stage 2 of rfft2: X[i64][j] = sum_y R[y][j] e^{-2pi i r(i64) y/128}.
// Grid: nplanes*2 blocks (32 i64 each). R staged in LDS as SoA (bank = j, conflict-free).
// Output mode-major: dst[(i64*32+j)*npl + plane].
__global__ __launch_bounds__(256, 4) void fwd_cols(const float2* __restrict__ R,
                                                   float2* __restrict__ dst,
                                                   const float* __restrict__ ws,
                                                   int npl) {
  int plane = blockIdx.x >> 1, half = blockIdx.x & 1;
  const float4* T2a = (const float4*)(ws + OFF_T2A);
  __shared__ float Rsr[4096], Rsi[4096]; // [y][j] SoA, 32 KB
  int t = threadIdx.x;
  const float2* Rp = R + (size_t)plane * 4096;
#pragma unroll
  for (int k = 0; k < 16; k++) {
    float2 v = Rp[t + 256 * k];
    Rsr[t + 256 * k] = v.x;
    Rsi[t + 256 * k] = v.y;
  }
  __syncthreads();
  int j = t & 31, ig = t >> 5;
  float xr[4] = {0.f, 0.f, 0.f, 0.f}, xi[4] = {0.f, 0.f, 0.f, 0.f};
  for (int y2 = 0; y2 < 64; y2++) {
    float r0r = Rsr[(2 * y2) * 32 + j],     r0i = Rsi[(2 * y2) * 32 + j];
    float r1r = Rsr[(2 * y2 + 1) * 32 + j], r1i = Rsi[(2 * y2 + 1) * 32 + j];
#pragma unroll
    for (int m = 0; m < 4; m++) {
      int i64 = half * 32 + ig + 8 * m;
      float4 tw = T2a[i64 * 64 + y2]; // (c0,s0,c1,s1), -angle baked in
      xr[m] += r0r * tw.x + r0i * tw.y + r1r * tw.z + r1i * tw.w;
      xi[m] += r0i * tw.x - r0r * tw.y + r1i * tw.z - r1r * tw.w;
    }
  }
#pragma unroll
  for (int m = 0; m < 4; m++) {
    int i64 = half * 32 + ig + 8 * m;
    dst[(size_t)(i64 * 32 + j) * npl + plane] = make_float2(xr[m], xi[m]);
  }
}

// Wk[mode][c][o] = Km[mode][c] * (w1|w2)[c][o][r][j]  (complex)
__global__ __launch_bounds__(256) void wk_build(const float* __restrict__ w1r,
                                                const float* __restrict__ w1i,
                                                const float* __restrict__ w2r,
                                                const float* __restrict__ w2i,
                                                float2* __restrict__ wk,
                                                const float2* __restrict__ km) {
  int e0 = blockIdx.x * 256 + threadIdx.x;
#pragma unroll
  for (int k = 0; k < 4; k++) {
    int e = e0 + k * 524288;
    int o = e & 31, c = (e >> 5) & 31, j = (e >> 10) & 31, i64 = e >> 15;
    int r = (i64 < 32) ? i64 : i64 - 32;
    const float* wr = (i64 < 32) ? w1r : w2r;
    const float* wi = (i64 < 32) ? w1i : w2i;
    int widx = ((c * 32 + o) * 32 + r) * 32 + j;
    float wrv = wr[widx], wiv = wi[widx];
    float2 kv = km[(i64 * 32 + j) * 32 + c];
    wk[e] = make_float2(kv.x * wrv - kv.y * wiv, kv.x * wiv + kv.y * wrv);
  }
}

// Per-mode channel mixing: Om[mode][bl][o] = sum_c Xm[mode][bl][c] * Wk[mode][c][o]
__global__ __launch_bounds__(256) void mix_modes(float2* __restrict__ xm,
                                                 const float2* __restrict__ wk) {
  int mode = blockIdx.x;
  __shared__ float2 Xs[1024]; // [bl][c]
  __shared__ float2 Ws[1024]; // [c][o]
  int t = threadIdx.x;
  size_t base = (size_t)mode * 1024;
#pragma unroll
  for (int k = 0; k < 4; k++) {
    Xs[t + 256 * k] = xm[base + t + 256 * k];
    Ws[t + 256 * k] = wk[base + t + 256 * k];
  }
  __syncthreads();
  int o = t & 31, bg = t >> 5;
  float orr[4], oii[4];
#pragma unroll
  for (int m = 0; m < 4; m++) { orr[m] = 0.f; oii[m] = 0.f; }
  for (int c = 0; c < 32; c++) {
    float2 wv = Ws[c * 32 + o];
#pragma unroll
    for (int m = 0; m < 4; m++) {
      float2 xv = Xs[(bg * 4 + m) * 32 + c];
      orr[m] += xv.x * wv.x - xv.y * wv.y;
      oii[m] += xv.x * wv.y + xv.y * wv.x;
    }
  }
#pragma unroll
  for (int m = 0; m < 4; m++)
    xm[base + (size_t)(bg * 4 + m) * 32 + o] = make_float2(orr[m], oii[m]);
}

// Inverse stage 1: G'[p][y][j] = scale * sum_{i64} Om[i64,j,p] e^{+2pi i r(i64) y/128}
// Scaling folded: j==0 -> (Re*inv, 0); j>=1 -> 2*inv*(Re,Im). Grid: 1024*2 blocks (64 y each).
__global__ __launch_bounds__(256, 4) void inv_rows(const float2* __restrict__ om,
                                                   float2* __restrict__ G,
                                                   const float* __restrict__ ws) {
  int p = blockIdx.x >> 1, half = blockIdx.x & 1;
  const float4* T2b = (const float4*)(ws + OFF_T2B);
  __shared__ float Osr[2048], Osi[2048]; // [i64][j] SoA, 16 KB
  int t = threadIdx.x;
#pragma unroll
  for (int k = 0; k < 8; k++) {
    float2 v = om[(size_t)(t + 256 * k) * 1024 + p];
    Osr[t + 256 * k] = v.x;
    Osi[t + 256 * k] = v.y;
  }
  __syncthreads();
  int j = t & 31, yg = t >> 5;
  float gr[8], gi[8];
#pragma unroll
  for (int k = 0; k < 8; k++) { gr[k] = 0.f; gi[k] = 0.f; }
  for (int i2 = 0; i2 < 32; i2++) {
    float o0r = Osr[(2 * i2) * 32 + j],     o0i = Osi[(2 * i2) * 32 + j];
    float o1r = Osr[(2 * i2 + 1) * 32 + j], o1i = Osi[(2 * i2 + 1) * 32 + j];
#pragma unroll
    for (int yy = 0; yy < 8; yy++) {
      int y = half * 64 + yg * 8 + yy;
      float4 tw = T2b[y * 32 + i2]; // (c0,s0,c1,s1), +angle
      gr[yy] += o0r * tw.x - o0i * tw.y + o1r * tw.z - o1i * tw.w;
      gi[yy] += o0r * tw.y + o0i * tw.x + o1r * tw.w + o1i * tw.z;
    }
  }
  const float inv = 1.0f / 32768.0f;
#pragma unroll
  for (int yy = 0; yy < 8; yy++) {
    int y = half * 64 + yg * 8 + yy;
    float sr = (j == 0) ? gr[yy] * inv : 2.f * inv * gr[yy];
    float si = (j == 0) ? 0.f : 2.f * inv * gi[yy];
    G[((size_t)p * Hn + y) * 32 + j] = make_float2(sr, si);
  }
}

// Inverse stage 2: out[y][x] = sum_{j=0}^{31} G'r[y][j] cos(2pi j x/256) - G'i[y][j] sin(...).
// Grid: 1024*4 blocks (32 y each). jj-outer / y-inner so twiddles load once per jj.
__global__ __launch_bounds__(256, 4) void inv_cols(const float2* __restrict__ G,
                                                   float* __restrict__ out,
                                                   const float* __restrict__ ws) {
  int p = blockIdx.x >> 2, chunk = blockIdx.x & 3;
  const float4* T1e = (const float4*)(ws + OFF_T1E);
  const float4* T1f = (const float4*)(ws + OFF_T1F);
  __shared__ float Gsr[1024], Gsi[1024]; // [y_local][j] SoA, 8 KB
  int t = threadIdx.x;
  const float2* Gp = G + (size_t)p * 4096 + chunk * 1024;
#pragma unroll
  for (int k = 0; k < 4; k++) {
    float2 v = Gp[t + 256 * k];
    Gsr[t + 256 * k] = v.x;
    Gsi[t + 256 * k] = v.y;
  }
  __syncthreads();
  int xq = t & 63, yg = t >> 6;
  float4 acc[8];
#pragma unroll
  for (int yy = 0; yy < 8; yy++) acc[yy] = make_float4(0.f, 0.f, 0.f, 0.f);
  for (int jj = 0; jj < 32; jj++) {
    float4 c4 = T1e[jj * 64 + xq];
    float4 s4 = T1f[jj * 64 + xq];
#pragma unroll
    for (int yy = 0; yy < 8; yy++) {
      float gr = Gsr[(yg * 8 + yy) * 32 + jj]; // wave-uniform broadcast
      float gi = Gsi[(yg * 8 + yy) * 32 + jj];
      acc[yy].x += gr * c4.x - gi * s4.x;
      acc[yy].y += gr * c4.y - gi * s4.y;
      acc[yy].z += gr * c4.z - gi * s4.z;
      acc[yy].w += gr * c4.w - gi * s4.w;
    }
  }
  float* outp = out + (size_t)p * PLANE + chunk * 32 * Wn;
#pragma unroll
  for (int yy = 0; yy < 8; yy++) {
    int y = yg * 8 + yy;
    *(float4*)(outp + y * Wn + xq * 4) = acc[yy];
  }
}

extern "C" void kernel_launch(void* const* d_in, const int* in_sizes, int n_in,
                              void* d_out, int out_size, void* d_ws, size_t ws_size,
                              hipStream_t stream) {
  (void)in_sizes; (void)n_in; (void)out_size; (void)ws_size;
  const float* x   = (const float*)d_in[0];
  const float* kk  = (const float*)d_in[1];
  const float* w1r = (const float*)d_in[2];
  const float* w1i = (const float*)d_in[3];
  const float* w2r = (const float*)d_in[4];
  const float* w2i = (const float*)d_in[5];
  float*  ws  = (float*)d_ws;
  float*  out = (float*)d_out;
  float2* km  = (float2*)(ws + OFF_KM);
  float2* xm  = (float2*)(ws + OFF_XM);
  float2* bx  = (float2*)(ws + OFF_B);   // Rx, then WK, then G'
  float2* rk  = (float2*)(ws + OFF_RK);

  build_tables<<<16, 256, 0, stream>>>(ws);
  // forward transform of x (Rx lives in B region)
  fwd_rows<<<4096, 256, 0, stream>>>(x, bx, ws);
  fwd_rows<<<128, 256, 0, stream>>>(kk, rk, ws);
  fwd_cols<<<2048, 256, 0, stream>>>(bx, xm, ws, 1024);
  fwd_cols<<<64, 256, 0, stream>>>(rk, km, ws, 32);
  // Rx dead -> build WK in B region
  wk_build<<<2048, 256, 0, stream>>>(w1r, w1i, w2r, w2i, bx, km);
  mix_modes<<<2048, 256, 0, stream>>>(xm, bx);
  // WK dead -> G' in B region
  inv_rows<<<2048, 256, 0, stream>>>(xm, bx, ws);
  inv_cols<<<4096, 256, 0, stream>>>(bx, out, ws);
}

// Round 4
// 453.368 us; speedup vs baseline: 2.3830x; 1.6545x over previous
//
#include <hip/hip_runtime.h>
#include <math.h>

#define Hn 128
#define Wn 256
#define PLANE (Hn*Wn)

// Workspace layout (float offsets)
#define OFF_TQC 0u        // [j<32][xi<16] float4: cos(2pi*j*(xi*4+m)/256), x<64 quarter
#define OFF_TQS 2048u     // sin
#define OFF_TP  4096u     // [p<32][y2<64] float4: (c,s) at y=2y2 and y=2y2+1, theta=2pi*p*y/128
#define OFF_KM  16384u    // [c=32][mode=2048] float2 (plane-major spectrum of k)
#define OFF_XM  147456u   // [plane=1024][mode=2048] float2
#define OFF_B   4341760u  // time-shared: R [1024][128][32] f2 -> WK [mode][c][o] f2 -> G' [1024][128][32] f2
#define OFF_RK  12730368u // Rk [32][128][32] float2
// total 12992512 floats = 49.6 MiB

__global__ __launch_bounds__(256) void build_tables(float* __restrict__ ws) {
  int tid = blockIdx.x * 256 + threadIdx.x; // 2048 threads
  const double PI2 = 6.283185307179586476925286766559;
  if (tid < 512) {
    int j = tid >> 4, xi = tid & 15;
    float cc[4], ss[4];
#pragma unroll
    for (int m = 0; m < 4; m++) {
      int x = xi * 4 + m;
      double ang = PI2 * (double)((j * x) & 255) / 256.0;
      cc[m] = (float)cos(ang); ss[m] = (float)sin(ang);
    }
    ((float4*)(ws + OFF_TQC))[tid] = make_float4(cc[0], cc[1], cc[2], cc[3]);
    ((float4*)(ws + OFF_TQS))[tid] = make_float4(ss[0], ss[1], ss[2], ss[3]);
  }
  if (tid < 2048) {
    int p = tid >> 6, y2 = tid & 63;
    double a0 = PI2 * (double)((p * (2 * y2)) & 127) / 128.0;
    double a1 = PI2 * (double)((p * (2 * y2 + 1)) & 127) / 128.0;
    ((float4*)(ws + OFF_TP))[tid] =
        make_float4((float)cos(a0), (float)sin(a0), (float)cos(a1), (float)sin(a1));
  }
}

__device__ __forceinline__ float rot_re(int m, float Sr, float Si) {
  return (m == 0) ? Sr : (m == 1) ? Si : (m == 2) ? -Sr : -Si;
}
__device__ __forceinline__ float rot_im(int m, float Sr, float Si) {
  return (m == 0) ? Si : (m == 1) ? -Sr : (m == 2) ? -Si : Sr;
}

// x-DFT: R[plane][y][j] = sum_x u[y,x] e^{-2pi i j x/256}, j<32.
// LDS-staged u tile (XOR swizzle) + quarter twiddle table; 2j x 2y x 4q accumulators.
__global__ __launch_bounds__(256) void fwd_rows(const float* __restrict__ src,
                                                float2* __restrict__ R,
                                                const float* __restrict__ ws) {
  int plane = blockIdx.x >> 2, chunk = blockIdx.x & 3;
  __shared__ float4 Us[2048];          // 32 y x 64 col4, swizzled
  __shared__ float4 Tc[544], Ts[544];  // [j][17] padded
  int t = threadIdx.x;
  const float4* src4 = (const float4*)src;
  size_t sb = (size_t)plane * 8192 + (size_t)chunk * 2048;
#pragma unroll
  for (int k = 0; k < 8; k++) {
    int idx = t + 256 * k;
    int row = idx >> 6, col4 = idx & 63;
    Us[row * 64 + (col4 ^ ((row >> 1) & 15))] = src4[sb + idx];
  }
  const float4* gTc = (const float4*)(ws + OFF_TQC);
  const float4* gTs = (const float4*)(ws + OFF_TQS);
#pragma unroll
  for (int k = 0; k < 2; k++) {
    int idx = t + 256 * k;
    Tc[(idx >> 4) * 17 + (idx & 15)] = gTc[idx];
    Ts[(idx >> 4) * 17 + (idx & 15)] = gTs[idx];
  }
  __syncthreads();
  int jg = t & 15, yg = t >> 4;
  float ar[2][2][4], ai[2][2][4];
#pragma unroll
  for (int a = 0; a < 2; a++)
#pragma unroll
    for (int b = 0; b < 2; b++)
#pragma unroll
      for (int q = 0; q < 4; q++) { ar[a][b][q] = 0.f; ai[a][b][q] = 0.f; }
  for (int xb = 0; xb < 16; xb++) {
    float4 c0 = Tc[jg * 17 + xb],        s0 = Ts[jg * 17 + xb];
    float4 c1 = Tc[(jg + 16) * 17 + xb], s1 = Ts[(jg + 16) * 17 + xb];
#pragma unroll
    for (int ky = 0; ky < 2; ky++) {
      int y = yg * 2 + ky;
      int sw = (y >> 1) & 15;
      int base = y * 64;
#pragma unroll
      for (int q = 0; q < 4; q++) {
        float4 u4 = Us[base + ((q * 16 + xb) ^ sw)];
        ar[0][ky][q] += u4.x * c0.x + u4.y * c0.y + u4.z * c0.z + u4.w * c0.w;
        ai[0][ky][q] -= u4.x * s0.x + u4.y * s0.y + u4.z * s0.z + u4.w * s0.w;
        ar[1][ky][q] += u4.x * c1.x + u4.y * c1.y + u4.z * c1.z + u4.w * c1.w;
        ai[1][ky][q] -= u4.x * s1.x + u4.y * s1.y + u4.z * s1.z + u4.w * s1.w;
      }
    }
  }
  // Combine quarters: R = sum_q (-i)^(j*q) * S_q, then store.
#pragma unroll
  for (int jj = 0; jj < 2; jj++) {
    int j = jg + 16 * jj;
    int m1 = j & 3, m2 = (2 * j) & 3, m3 = (3 * j) & 3;
#pragma unroll
    for (int ky = 0; ky < 2; ky++) {
      int y = chunk * 32 + yg * 2 + ky;
      float re = ar[jj][ky][0], im = ai[jj][ky][0];
      re += rot_re(m1, ar[jj][ky][1], ai[jj][ky][1]);
      im += rot_im(m1, ar[jj][ky][1], ai[jj][ky][1]);
      re += rot_re(m2, ar[jj][ky][2], ai[jj][ky][2]);
      im += rot_im(m2, ar[jj][ky][2], ai[jj][ky][2]);
      re += rot_re(m3, ar[jj][ky][3], ai[jj][ky][3]);
      im += rot_im(m3, ar[jj][ky][3], ai[jj][ky][3]);
      R[((size_t)plane * 128 + y) * 32 + j] = make_float2(re, im);
    }
  }
}

// y-DFT with row pairing (r, r+96): factor i^y. Output plane-major dst[plane][i64*32+j].
__global__ __launch_bounds__(256) void fwd_cols(const float2* __restrict__ Rg,
                                                float2* __restrict__ dst,
                                                const float* __restrict__ ws) {
  int plane = blockIdx.x;
  __shared__ float4 Rs4[2048];   // [y=128][j=32] float2 = 2048 float4 (32 KB)
  __shared__ float4 TPs[2048];   // [p][y2] (32 KB)
  float2* Rs = (float2*)Rs4;
  int t = threadIdx.x;
  const float4* in4 = (const float4*)(Rg + (size_t)plane * 4096);
#pragma unroll
  for (int k = 0; k < 8; k++) Rs4[t + 256 * k] = in4[t + 256 * k];
  const float4* gTP = (const float4*)(ws + OFF_TP);
#pragma unroll
  for (int k = 0; k < 8; k++) TPs[t + 256 * k] = gTP[t + 256 * k];
  __syncthreads();
  int j = t & 31, pg = t >> 5;
  float Are[4], Aim[4], Bre[4], Bim[4];
#pragma unroll
  for (int m = 0; m < 4; m++) { Are[m] = Aim[m] = Bre[m] = Bim[m] = 0.f; }
  for (int it = 0; it < 32; it++) {
#pragma unroll
    for (int h = 0; h < 2; h++) {
      int y2 = 2 * it + h;
      float sg = (h == 0) ? 1.f : -1.f;  // (-1)^y2
      float2 r0 = Rs[(2 * y2) * 32 + j];
      float2 r1 = Rs[(2 * y2 + 1) * 32 + j];
#pragma unroll
      for (int m = 0; m < 4; m++) {
        int p = pg + 8 * m;
        float4 tw = TPs[p * 64 + y2];
        float P0 = r0.x * tw.x + r0.y * tw.y;
        float Q0 = r0.y * tw.x - r0.x * tw.y;
        float P1 = r1.x * tw.z + r1.y * tw.w;
        float Q1 = r1.y * tw.z - r1.x * tw.w;
        Are[m] += P0 + P1;
        Aim[m] += Q0 + Q1;
        Bre[m] += sg * (P0 - Q1);   // i^y fold: even +sg*(P,Q); odd +sg*(-Q,P)
        Bim[m] += sg * (Q0 + P1);
      }
    }
  }
  size_t ob = (size_t)plane * 2048;
#pragma unroll
  for (int m = 0; m < 4; m++) {
    int p = pg + 8 * m;
    dst[ob + p * 32 + j] = make_float2(Are[m], Aim[m]);
    dst[ob + (32 + p) * 32 + j] = make_float2(Bre[m], Bim[m]);
  }
}

// Wk[mode][c][o] = Km[c][mode] * (w1|w2)[c][o][r][j]
__global__ __launch_bounds__(256) void wk_build(const float* __restrict__ w1r,
                                                const float* __restrict__ w1i,
                                                const float* __restrict__ w2r,
                                                const float* __restrict__ w2i,
                                                float2* __restrict__ wk,
                                                const float2* __restrict__ km) {
  int e0 = blockIdx.x * 256 + threadIdx.x;
#pragma unroll
  for (int k = 0; k < 4; k++) {
    int e = e0 + k * 524288;
    int o = e & 31, c = (e >> 5) & 31, j = (e >> 10) & 31, i64 = e >> 15;
    int r = (i64 < 32) ? i64 : i64 - 32;
    const float* wr = (i64 < 32) ? w1r : w2r;
    const float* wi = (i64 < 32) ? w1i : w2i;
    int widx = ((c * 32 + o) * 32 + r) * 32 + j;
    float wrv = wr[widx], wiv = wi[widx];
    float2 kv = km[(size_t)c * 2048 + i64 * 32 + j];
    wk[e] = make_float2(kv.x * wrv - kv.y * wiv, kv.x * wiv + kv.y * wrv);
  }
}

// Per-mode channel mixing on plane-major xm; XCD-swizzled gather/scatter.
__global__ __launch_bounds__(256) void mix_modes(float2* __restrict__ xm,
                                                 const float2* __restrict__ wk) {
  int bid = blockIdx.x;
  int mode = (bid & 7) * 256 + (bid >> 3);
  __shared__ float4 Xs4[512], Ws4[512];
  float2* Xs = (float2*)Xs4;
  float2* Wsl = (float2*)Ws4;
  int t = threadIdx.x;
#pragma unroll
  for (int k = 0; k < 4; k++) {
    int p = t + 256 * k;
    Xs[p] = xm[(size_t)p * 2048 + mode];
  }
  const float4* wk4 = (const float4*)(wk + (size_t)mode * 1024);
#pragma unroll
  for (int k = 0; k < 2; k++) Ws4[t + 256 * k] = wk4[t + 256 * k];
  __syncthreads();
  int o = t & 31, bg = t >> 5;
  float orr[4], oii[4];
#pragma unroll
  for (int m = 0; m < 4; m++) { orr[m] = 0.f; oii[m] = 0.f; }
  for (int c2 = 0; c2 < 16; c2++) {
    float2 w0 = Wsl[(2 * c2) * 32 + o];
    float2 w1 = Wsl[(2 * c2 + 1) * 32 + o];
#pragma unroll
    for (int m = 0; m < 4; m++) {
      float4 xv = *(const float4*)&Xs[(bg * 4 + m) * 32 + 2 * c2];
      orr[m] += xv.x * w0.x - xv.y * w0.y + xv.z * w1.x - xv.w * w1.y;
      oii[m] += xv.x * w0.y + xv.y * w0.x + xv.z * w1.y + xv.w * w1.x;
    }
  }
#pragma unroll
  for (int m = 0; m < 4; m++)
    xm[(size_t)((bg * 4 + m) * 32 + o) * 2048 + mode] = make_float2(orr[m], oii[m]);
}

// Inverse y-DFT with pairing: G[y] = sum_p (A_p + (-i)^y B_p) e^{+i theta_py}; scaling folded.
__global__ __launch_bounds__(256) void inv_rows(const float2* __restrict__ om,
                                                float2* __restrict__ G,
                                                const float* __restrict__ ws) {
  int plane = blockIdx.x;
  __shared__ float4 Os4[1024];   // [i64][j] float2 (2048 float2)
  __shared__ float4 TPs[2048];
  float2* Os = (float2*)Os4;
  int t = threadIdx.x;
  const float4* in4 = (const float4*)(om + (size_t)plane * 2048);
#pragma unroll
  for (int k = 0; k < 4; k++) Os4[t + 256 * k] = in4[t + 256 * k];
  const float4* gTP = (const float4*)(ws + OFF_TP);
#pragma unroll
  for (int k = 0; k < 8; k++) TPs[t + 256 * k] = gTP[t + 256 * k];
  __syncthreads();
  int j = t & 31, yg = t >> 5;
  float gr[16], gi[16];
#pragma unroll
  for (int k = 0; k < 16; k++) { gr[k] = 0.f; gi[k] = 0.f; }
  for (int p = 0; p < 32; p++) {
    float2 A = Os[p * 32 + j];
    float2 B = Os[(32 + p) * 32 + j];
#pragma unroll
    for (int mp = 0; mp < 8; mp++) {
      int y2 = yg * 8 + mp;
      float4 tw = TPs[p * 64 + y2];
      float sg = ((mp & 1) == 0) ? 1.f : -1.f;  // (-1)^y2
      float Sr = A.x + sg * B.x, Si = A.y + sg * B.y;          // y even
      gr[2 * mp]     += Sr * tw.x - Si * tw.y;
      gi[2 * mp]     += Sr * tw.y + Si * tw.x;
      float Tr = A.x + sg * B.y, Ti = A.y - sg * B.x;          // y odd: +sg*(-i)B
      gr[2 * mp + 1] += Tr * tw.z - Ti * tw.w;
      gi[2 * mp + 1] += Tr * tw.w + Ti * tw.z;
    }
  }
  const float inv = 1.0f / 32768.0f;
  size_t gb = (size_t)plane * 128;
#pragma unroll
  for (int mm = 0; mm < 16; mm++) {
    int y = yg * 16 + mm;
    float sr = (j == 0) ? gr[mm] * inv : 2.f * inv * gr[mm];
    float si = (j == 0) ? 0.f : 2.f * inv * gi[mm];
    G[(gb + y) * 32 + j] = make_float2(sr, si);
  }
}

// Inverse x-DFT: out[y][x] = sum_jj Re(G[y][jj] e^{+2pi i jj x/256}); quarter-folded twiddles.
__global__ __launch_bounds__(256) void inv_cols(const float2* __restrict__ G,
                                                float* __restrict__ out,
                                                const float* __restrict__ ws) {
  int plane = blockIdx.x >> 2, chunk = blockIdx.x & 3;
  __shared__ float2 Gs[32 * 33];       // padded [yl][33]
  __shared__ float4 Tc[544], Ts[544];  // [jj][17] padded
  int t = threadIdx.x;
  const float2* in = G + (size_t)plane * 4096 + (size_t)chunk * 1024;
#pragma unroll
  for (int k = 0; k < 4; k++) {
    int idx = t + 256 * k;
    Gs[(idx >> 5) * 33 + (idx & 31)] = in[idx];
  }
  const float4* gTc = (const float4*)(ws + OFF_TQC);
  const float4* gTs = (const float4*)(ws + OFF_TQS);
#pragma unroll
  for (int k = 0; k < 2; k++) {
    int idx = t + 256 * k;
    Tc[(idx >> 4) * 17 + (idx & 15)] = gTc[idx];
    Ts[(idx >> 4) * 17 + (idx & 15)] = gTs[idx];
  }
  __syncthreads();
  int xi = t & 15, yg = t >> 4;
  float4 acc[2][4];
#pragma unroll
  for (int ky = 0; ky < 2; ky++)
#pragma unroll
    for (int q = 0; q < 4; q++) acc[ky][q] = make_float4(0.f, 0.f, 0.f, 0.f);
  for (int jjb = 0; jjb < 8; jjb++) {
#pragma unroll
    for (int jjo = 0; jjo < 4; jjo++) {
      int jj = jjb * 4 + jjo;
      float4 c4 = Tc[jj * 17 + xi];
      float4 s4 = Ts[jj * 17 + xi];
#pragma unroll
      for (int ky = 0; ky < 2; ky++) {
        float2 g = Gs[(yg * 2 + ky) * 33 + jj];
        float4 P, Q;
        P.x = g.x * c4.x - g.y * s4.x;  P.y = g.x * c4.y - g.y * s4.y;
        P.z = g.x * c4.z - g.y * s4.z;  P.w = g.x * c4.w - g.y * s4.w;
        Q.x = g.x * s4.x + g.y * c4.x;  Q.y = g.x * s4.y + g.y * c4.y;
        Q.z = g.x * s4.z + g.y * c4.z;  Q.w = g.x * s4.w + g.y * c4.w;
#pragma unroll
        for (int q = 0; q < 4; q++) {
          int m = (jjo * q) & 3;  // contribution of quarter q: i^(jj*q) fold
          if (m == 0) {
            acc[ky][q].x += P.x; acc[ky][q].y += P.y; acc[ky][q].z += P.z; acc[ky][q].w += P.w;
          } else if (m == 1) {
            acc[ky][q].x -= Q.x; acc[ky][q].y -= Q.y; acc[ky][q].z -= Q.z; acc[ky][q].w -= Q.w;
          } else if (m == 2) {
            acc[ky][q].x -= P.x; acc[ky][q].y -= P.y; acc[ky][q].z -= P.z; acc[ky][q].w -= P.w;
          } else {
            acc[ky][q].x += Q.x; acc[ky][q].y += Q.y; acc[ky][q].z += Q.z; acc[ky][q].w += Q.w;
          }
        }
      }
    }
  }
  float* outp = out + (size_t)plane * PLANE + (size_t)chunk * 32 * Wn;
#pragma unroll
  for (int ky = 0; ky < 2; ky++) {
    int y = yg * 2 + ky;
#pragma unroll
    for (int q = 0; q < 4; q++)
      *(float4*)(outp + y * Wn + q * 64 + xi * 4) = acc[ky][q];
  }
}

extern "C" void kernel_launch(void* const* d_in, const int* in_sizes, int n_in,
                              void* d_out, int out_size, void* d_ws, size_t ws_size,
                              hipStream_t stream) {
  (void)in_sizes; (void)n_in; (void)out_size; (void)ws_size;
  const float* x   = (const float*)d_in[0];
  const float* kk  = (const float*)d_in[1];
  const float* w1r = (const float*)d_in[2];
  const float* w1i = (const float*)d_in[3];
  const float* w2r = (const float*)d_in[4];
  const float* w2i = (const float*)d_in[5];
  float*  ws   = (float*)d_ws;
  float*  out  = (float*)d_out;
  float2* km2  = (float2*)(ws + OFF_KM);
  float2* xm2  = (float2*)(ws + OFF_XM);
  float2* bx   = (float2*)(ws + OFF_B);   // R -> WK -> G'
  float2* rk   = (float2*)(ws + OFF_RK);

  build_tables<<<8, 256, 0, stream>>>(ws);
  fwd_rows<<<4096, 256, 0, stream>>>(x, bx, ws);
  fwd_rows<<<128, 256, 0, stream>>>(kk, rk, ws);
  fwd_cols<<<1024, 256, 0, stream>>>(bx, xm2, ws);
  fwd_cols<<<32, 256, 0, stream>>>(rk, km2, ws);
  wk_build<<<2048, 256, 0, stream>>>(w1r, w1i, w2r, w2i, bx, km2);
  mix_modes<<<2048, 256, 0, stream>>>(xm2, bx);
  inv_rows<<<1024, 256, 0, stream>>>(xm2, bx, ws);
  inv_cols<<<4096, 256, 0, stream>>>(bx, out, ws);
}